// Round 1
// baseline (68.531 us; speedup 1.0000x reference)
//
#include <hip/hip_runtime.h>

// Problem constants (from reference setup_inputs)
#define BB 32     // batch
#define UU 1152   // input_units
#define NN 10     // num_units
#define CC 8      // input_channels
#define DD 16     // channels_per_unit
#define ITERS 3
#define EPS 1e-8f

// inputs : (B, C, U)          float32
// weights: (U, N, C, D)       float32
// out    : (B, N, U, C, D)    float32
//
// pondered[b,u,n,c,d] = weights[u,n,c,d] * inputs[b,c,u]
// routing (softmax over d, squash over d, logits += pondered*out) is fully
// local to the 16-element (b,u,n,c,:) vector -> one thread per group.

__global__ __launch_bounds__(256) void caps_route_kernel(
    const float* __restrict__ inputs,
    const float* __restrict__ weights,
    float* __restrict__ out)
{
    long long t = (long long)blockIdx.x * blockDim.x + threadIdx.x;
    const long long total = (long long)BB * NN * UU * CC;
    if (t >= total) return;

    // decode: c fastest (8), then u (1152), then n (10), then b
    int c = (int)(t & 7);
    long long t2 = t >> 3;
    int u = (int)(t2 % UU);
    long long t3 = t2 / UU;
    int n = (int)(t3 % NN);
    int b = (int)(t3 / NN);

    float v = inputs[((long long)b * CC + c) * UU + u];
    const float* wp = weights + (((long long)u * NN + n) * CC + c) * DD;

    float p[DD];
    #pragma unroll
    for (int i = 0; i < DD; i += 4) {
        float4 w4 = *reinterpret_cast<const float4*>(wp + i);
        p[i]   = w4.x * v;
        p[i+1] = w4.y * v;
        p[i+2] = w4.z * v;
        p[i+3] = w4.w * v;
    }

    float logits[DD];
    #pragma unroll
    for (int i = 0; i < DD; ++i) logits[i] = 0.0f;

    float o[DD];
    #pragma unroll
    for (int it = 0; it < ITERS; ++it) {
        float s[DD];
        float sq = 0.0f;
        if (it == 0) {
            // logits are all zero -> softmax is uniform 1/16
            #pragma unroll
            for (int i = 0; i < DD; ++i) {
                s[i] = 0.0625f * p[i];
                sq += s[i] * s[i];
            }
        } else {
            // softmax over the 16 logits (in registers)
            float m = logits[0];
            #pragma unroll
            for (int i = 1; i < DD; ++i) m = fmaxf(m, logits[i]);
            float e[DD];
            float sum = 0.0f;
            #pragma unroll
            for (int i = 0; i < DD; ++i) {
                e[i] = __expf(logits[i] - m);
                sum += e[i];
            }
            float inv = 1.0f / sum;
            #pragma unroll
            for (int i = 0; i < DD; ++i) {
                s[i] = e[i] * inv * p[i];
                sq += s[i] * s[i];
            }
        }
        // squash: (sq/(1+sq)) * s / sqrt(sq+eps)
        float scale = (sq / (1.0f + sq)) * rsqrtf(sq + EPS);
        #pragma unroll
        for (int i = 0; i < DD; ++i) {
            o[i] = scale * s[i];
            logits[i] = fmaf(p[i], o[i], logits[i]);
        }
    }

    // out offset: (((b*N + n)*U + u)*C + c)*D  -> 64 contiguous bytes/thread
    float* op = out + ((((long long)b * NN + n) * UU + u) * CC + c) * DD;
    #pragma unroll
    for (int i = 0; i < DD; i += 4) {
        float4 r;
        r.x = o[i]; r.y = o[i+1]; r.z = o[i+2]; r.w = o[i+3];
        *reinterpret_cast<float4*>(op + i) = r;
    }
}

extern "C" void kernel_launch(void* const* d_in, const int* in_sizes, int n_in,
                              void* d_out, int out_size, void* d_ws, size_t ws_size,
                              hipStream_t stream) {
    const float* inputs  = (const float*)d_in[0];
    const float* weights = (const float*)d_in[1];
    float* out = (float*)d_out;

    const long long total = (long long)BB * NN * UU * CC;  // 2,949,120
    const int block = 256;
    const int grid = (int)((total + block - 1) / block);   // 11,520
    caps_route_kernel<<<grid, block, 0, stream>>>(inputs, weights, out);
}